// Round 4
// baseline (331.366 us; speedup 1.0000x reference)
//
#include <hip/hip_runtime.h>

#define NODES 14
#define IN_F 24
#define HID1 32
#define HID2 64
#define OUT_F 24
#define SLOPE 0.2f

#define GPB 4     // graphs per block (2 waves each -> 512 threads)
#define XS_S 28   // xs stride in arena
#define H1_S 36   // h1s stride in arena
#define H2_S 68   // h2s stride in arena
#define BIG (NODES * H2_S)  // 952 floats: xs -> h1s -> h2s overlay

__global__ __launch_bounds__(128 * GPB, 4) void gnn_fused(
    const float* __restrict__ x, const float* __restrict__ y,
    const float* __restrict__ W1, const float* __restrict__ a_src1,
    const float* __restrict__ a_dst1, const float* __restrict__ b1,
    const float* __restrict__ W2, const float* __restrict__ a_src2,
    const float* __restrict__ a_dst2, const float* __restrict__ b2,
    const float* __restrict__ Wf1, const float* __restrict__ bf1,
    const float* __restrict__ Wf2, const float* __restrict__ bf2,
    float* __restrict__ out, int ngraphs)
{
  const int tid  = threadIdx.x;
  const int gl   = tid >> 7;         // graph-in-block 0..3
  const int t    = tid & 127;        // per-graph thread
  const int lane = tid & 63;
  const int wid  = (tid >> 6) & 1;   // wave within graph
  const int g    = blockIdx.x * GPB + gl;
  const bool act = g < ngraphs;

  // block-shared precontracted attention vectors: u = W @ a
  __shared__ float us1[2 * IN_F], ud1[2 * IN_F];   // 96
  __shared__ float us2[2 * HID1], ud2[2 * HID1];   // 128
  // per-graph arenas
  __shared__ __align__(16) float big[GPB][BIG];    // xs / h1s / h2s overlay
  __shared__ float watt[GPB][NODES * 28];
  __shared__ float als[GPB][28], ald[GPB][28];
  __shared__ float hhs[GPB][112];

  float* const arena = big[gl];

  // ---- independent y-copy (hide store latency under compute) ----
  if (act && t < (NODES * OUT_F) / 4) {
    const float4* y4 = (const float4*)(y + (size_t)g * (NODES * OUT_F));
    float4* o4 = (float4*)(out + (size_t)NODES * ngraphs * OUT_F
                               + (size_t)g * (NODES * OUT_F));
    o4[t] = y4[t];
  }

  // ---- stage x into arena (float4, padded stride) ----
  if (act && t < (NODES * IN_F) / 4) {
    const float4 v = *(const float4*)(x + (size_t)g * (NODES * IN_F) + t * 4);
    const int n = (t * 4) / IN_F, k = (t * 4) - n * IN_F;
    *(float4*)&arena[n * XS_S + k] = v;
  }

  // ---- u-vectors, once per block (224 dots, register-light) ----
  if (tid < 224) {
    if (tid < 96) {
      const int sd = (tid >= 48), r = tid - sd * 48;
      const int h = (r >= IN_F), k = r - h * IN_F;
      const float* av = sd ? a_dst1 : a_src1;
      float s = 0.f;
#pragma unroll 8
      for (int f = 0; f < HID1; ++f)
        s += W1[k * 64 + h * HID1 + f] * av[h * HID1 + f];
      (sd ? ud1 : us1)[h * IN_F + k] = s;
    } else {
      const int j = tid - 96;
      const int sd = (j >= 64), r = j - sd * 64;
      const int h = (r >= HID1), k = r - h * HID1;
      const float* av = sd ? a_dst2 : a_src2;
      float s = 0.f;
#pragma unroll 8
      for (int f = 0; f < HID2; ++f)
        s += W2[k * 128 + h * HID2 + f] * av[h * HID2 + f];
      (sd ? ud2 : us2)[h * HID1 + k] = s;
    }
  }
  __syncthreads();

  // ---- layer1 GEMM: col = lane (both waves of the graph duplicate) ----
  float xcol[NODES];
  {
    float w[IN_F];
#pragma unroll
    for (int k = 0; k < IN_F; ++k) w[k] = W1[k * 64 + lane];
#pragma unroll
    for (int n = 0; n < NODES; ++n) {
      float acc = 0.f;
#pragma unroll
      for (int k4 = 0; k4 < IN_F / 4; ++k4) {
        const float4 xv = *(const float4*)&arena[n * XS_S + k4 * 4];
        acc += xv.x * w[k4 * 4 + 0] + xv.y * w[k4 * 4 + 1]
             + xv.z * w[k4 * 4 + 2] + xv.w * w[k4 * 4 + 3];
      }
      xcol[n] = acc;
    }
  }

  // ---- layer1 logits: al[n,h] = x[n,:] . u1[h,:]  (56 lanes/graph) ----
  if (t < 56) {
    const int n = t >> 2, h = (t >> 1) & 1, sd = t & 1;
    const float* uu = (sd ? ud1 : us1) + h * IN_F;
    float s = 0.f;
#pragma unroll
    for (int k = 0; k < IN_F; ++k) s += arena[n * XS_S + k] * uu[k];
    (sd ? ald : als)[gl][n * 2 + h] = s;
  }
  __syncthreads();

  // ---- layer1 softmax (28 lanes/graph) ----
  if (t < NODES * 2) {
    const int h = t & 1;
    const float ad = ald[gl][t];
    float a[NODES]; float m = -1e30f;
#pragma unroll
    for (int i = 0; i < NODES; ++i) {
      float v = als[gl][i * 2 + h] + ad;
      v = v > 0.f ? v : SLOPE * v;
      a[i] = v; m = fmaxf(m, v);
    }
    float den = 0.f;
#pragma unroll
    for (int i = 0; i < NODES; ++i) { a[i] = __expf(a[i] - m); den += a[i]; }
    const float r = 1.f / den;
#pragma unroll
    for (int i = 0; i < NODES; ++i) watt[gl][i * 28 + t] = a[i] * r;
  }
  __syncthreads();

  // ---- layer1 aggregate: wave wid does nodes [7*wid, 7*wid+7) ----
  {
    const int h = lane >> 5, f5 = lane & 31;
    const float bb = b1[f5];
#pragma unroll
    for (int tt = 0; tt < NODES / 2; ++tt) {
      const int n = wid * (NODES / 2) + tt;
      float o = 0.f;
#pragma unroll
      for (int i = 0; i < NODES; ++i)
        o += watt[gl][i * 28 + n * 2 + h] * xcol[i];
      const float oo = __shfl_xor(o, 32);
      if (h == 0) {
        const float v = 0.5f * (o + oo) + bb;
        arena[n * H1_S + f5] = v > 0.f ? v : expm1f(v);  // h1s over xs
      }
    }
  }
  __syncthreads();

  // ---- layer2 GEMM: col = t (128 cols, one per thread) ----
  float x2c[NODES];
  {
    float w2[HID1];
#pragma unroll
    for (int k = 0; k < HID1; ++k) w2[k] = W2[k * 128 + t];
#pragma unroll
    for (int n = 0; n < NODES; ++n) {
      float acc = 0.f;
#pragma unroll
      for (int k4 = 0; k4 < HID1 / 4; ++k4) {
        const float4 hv = *(const float4*)&arena[n * H1_S + k4 * 4];
        acc += hv.x * w2[k4 * 4 + 0] + hv.y * w2[k4 * 4 + 1]
             + hv.z * w2[k4 * 4 + 2] + hv.w * w2[k4 * 4 + 3];
      }
      x2c[n] = acc;
    }
  }

  // ---- layer2 logits: al[n,h] = h1[n,:] . u2[h,:]  (56 lanes/graph) ----
  if (t < 56) {
    const int n = t >> 2, h = (t >> 1) & 1, sd = t & 1;
    const float* uu = (sd ? ud2 : us2) + h * HID1;
    float s = 0.f;
#pragma unroll
    for (int k = 0; k < HID1; ++k) s += arena[n * H1_S + k] * uu[k];
    (sd ? ald : als)[gl][n * 2 + h] = s;
  }
  __syncthreads();

  // ---- layer2 softmax ----
  if (t < NODES * 2) {
    const int h = t & 1;
    const float ad = ald[gl][t];
    float a[NODES]; float m = -1e30f;
#pragma unroll
    for (int i = 0; i < NODES; ++i) {
      float v = als[gl][i * 2 + h] + ad;
      v = v > 0.f ? v : SLOPE * v;
      a[i] = v; m = fmaxf(m, v);
    }
    float den = 0.f;
#pragma unroll
    for (int i = 0; i < NODES; ++i) { a[i] = __expf(a[i] - m); den += a[i]; }
    const float r = 1.f / den;
#pragma unroll
    for (int i = 0; i < NODES; ++i) watt[gl][i * 28 + t] = a[i] * r;
  }
  __syncthreads();

  // ---- layer2 aggregate: head = wid; cross-wave combine via LDS ----
  {
    float agg[NODES];
#pragma unroll
    for (int n = 0; n < NODES; ++n) {
      float o = 0.f;
#pragma unroll
      for (int i = 0; i < NODES; ++i)
        o += watt[gl][i * 28 + n * 2 + wid] * x2c[i];
      agg[n] = o;
    }
    if (wid == 1) {
#pragma unroll
      for (int n = 0; n < NODES; ++n) arena[n * H2_S + lane] = agg[n];  // h2s over h1s
    }
    __syncthreads();
    if (wid == 0) {
      const float bb = b2[lane];
#pragma unroll
      for (int n = 0; n < NODES; ++n)
        arena[n * H2_S + lane] = 0.5f * (agg[n] + arena[n * H2_S + lane]) + bb;
    }
  }
  __syncthreads();

  // ---- per-node MLP layer 1 (112 lanes/graph) ----
  if (t < NODES * 8) {
    const int k = t >> 3, e = t & 7;
    float acc = bf1[k * 8 + e];
#pragma unroll 8
    for (int f = 0; f < HID2; ++f)
      acc += arena[k * H2_S + f] * Wf1[(k * HID2 + f) * 8 + e];
    hhs[gl][t] = fmaxf(acc, 0.f);
  }
  __syncthreads();

  // ---- per-node MLP layer 2 (336 outputs/graph) ----
  if (act) {
    for (int idx = t; idx < NODES * OUT_F; idx += 128) {
      const int k = idx / OUT_F, o = idx - k * OUT_F;
      float acc = bf2[k * OUT_F + o];
#pragma unroll
      for (int e = 0; e < 8; ++e)
        acc += hhs[gl][k * 8 + e] * Wf2[(k * 8 + e) * OUT_F + o];
      out[(size_t)k * ngraphs * OUT_F + (size_t)g * OUT_F + o] =
          1.f / (1.f + __expf(-acc));
    }
  }
}

extern "C" void kernel_launch(void* const* d_in, const int* in_sizes, int n_in,
                              void* d_out, int out_size, void* d_ws, size_t ws_size,
                              hipStream_t stream) {
  const float* x      = (const float*)d_in[0];
  const float* y      = (const float*)d_in[1];
  // d_in[2] = edge_index, d_in[3] = batch : structure fixed, unused
  const float* W1     = (const float*)d_in[4];
  const float* a_src1 = (const float*)d_in[5];
  const float* a_dst1 = (const float*)d_in[6];
  const float* b1     = (const float*)d_in[7];
  const float* W2     = (const float*)d_in[8];
  const float* a_src2 = (const float*)d_in[9];
  const float* a_dst2 = (const float*)d_in[10];
  const float* b2     = (const float*)d_in[11];
  const float* Wf1    = (const float*)d_in[12];
  const float* bf1    = (const float*)d_in[13];
  const float* Wf2    = (const float*)d_in[14];
  const float* bf2    = (const float*)d_in[15];
  float* out = (float*)d_out;

  const int nnodes  = in_sizes[0] / IN_F;
  const int ngraphs = nnodes / NODES;
  const int nblocks = (ngraphs + GPB - 1) / GPB;

  hipLaunchKernelGGL(gnn_fused, dim3(nblocks), dim3(128 * GPB), 0, stream,
                     x, y, W1, a_src1, a_dst1, b1, W2, a_src2, a_dst2, b2,
                     Wf1, bf1, Wf2, bf2, out, ngraphs);
}

// Round 5
// 320.821 us; speedup vs baseline: 1.0329x; 1.0329x over previous
//
#include <hip/hip_runtime.h>

#define NODES 14
#define IN_F 24
#define HID1 32
#define HID2 64
#define OUT_F 24
#define SLOPE 0.2f

#define XS_S 28   // xs stride   (float4-aligned)
#define H1_S 36   // h1s stride  (float4-aligned)
#define H2_S 68   // h2s stride

// u-vector layout in d_ws: us1[48] ud1[48] us2[64] ud2[64]  (224 floats)
#define U_US1 0
#define U_UD1 48
#define U_US2 96
#define U_UD2 160
#define U_TOT 224

// ---- kernel 1: precompute u = W @ a  (graph-invariant, once) ----
__global__ __launch_bounds__(256) void compute_uvecs(
    const float* __restrict__ W1, const float* __restrict__ a_src1,
    const float* __restrict__ a_dst1,
    const float* __restrict__ W2, const float* __restrict__ a_src2,
    const float* __restrict__ a_dst2, float* __restrict__ u)
{
  const int tid = threadIdx.x;
  if (tid < 96) {
    const int sd = (tid >= 48), r = tid - sd * 48;
    const int h = (r >= IN_F), k = r - h * IN_F;
    const float* av = sd ? a_dst1 : a_src1;
    float s = 0.f;
#pragma unroll
    for (int f = 0; f < HID1; ++f)
      s += W1[k * 64 + h * HID1 + f] * av[h * HID1 + f];
    u[(sd ? U_UD1 : U_US1) + h * IN_F + k] = s;
  } else if (tid < 224) {
    const int j = tid - 96;
    const int sd = (j >= 64), r = j - sd * 64;
    const int h = (r >= HID1), k = r - h * HID1;
    const float* av = sd ? a_dst2 : a_src2;
    float s = 0.f;
#pragma unroll
    for (int f = 0; f < HID2; ++f)
      s += W2[k * 128 + h * HID2 + f] * av[h * HID2 + f];
    u[(sd ? U_UD2 : U_US2) + h * HID1 + k] = s;
  }
}

// ---- kernel 2: fused GNN+MLP, one graph per 128-thread block ----
__global__ __launch_bounds__(128, 4) void gnn_fused(
    const float* __restrict__ x, const float* __restrict__ y,
    const float* __restrict__ W1, const float* __restrict__ b1,
    const float* __restrict__ W2, const float* __restrict__ b2,
    const float* __restrict__ Wf1, const float* __restrict__ bf1,
    const float* __restrict__ Wf2, const float* __restrict__ bf2,
    const float* __restrict__ uvec,
    float* __restrict__ out, int ngraphs)
{
  const int g = blockIdx.x;
  const int tid = threadIdx.x;
  const int lane = tid & 63;
  const int wid = tid >> 6;

  __shared__ float u[U_TOT];                         // 224
  __shared__ __align__(16) float xs[NODES * XS_S];   // 392
  __shared__ __align__(16) float h1s[NODES * H1_S];  // 504
  __shared__ float h2s[NODES * H2_S];                // 952
  __shared__ float watt[NODES * 28];                 // 392 [i][j][h]
  __shared__ float als[28], ald[28];
  __shared__ float hhs[112];

  // ---- stage u + x; y-copy (independent, hides store latency) ----
  if (tid < (NODES * OUT_F) / 4) {
    const float4* y4 = (const float4*)(y + (size_t)g * (NODES * OUT_F));
    float4* o4 = (float4*)(out + (size_t)NODES * ngraphs * OUT_F
                               + (size_t)g * (NODES * OUT_F));
    o4[tid] = y4[tid];
  }
  for (int i = tid; i < U_TOT; i += 128) u[i] = uvec[i];
  if (tid < (NODES * IN_F) / 4) {
    const float4 v = *(const float4*)(x + (size_t)g * (NODES * IN_F) + tid * 4);
    const int n = (tid * 4) / IN_F, k = (tid * 4) - n * IN_F;
    *(float4*)&xs[n * XS_S + k] = v;
  }
  __syncthreads();

  // ---- layer1 GEMM: col = lane (both waves duplicate; keeps xcol local) ----
  float xcol[NODES];
  {
    float w[IN_F];
#pragma unroll
    for (int k = 0; k < IN_F; ++k) w[k] = W1[k * 64 + lane];
#pragma unroll
    for (int n = 0; n < NODES; ++n) {
      float acc = 0.f;
#pragma unroll
      for (int k4 = 0; k4 < IN_F / 4; ++k4) {
        const float4 xv = *(const float4*)&xs[n * XS_S + k4 * 4];
        acc += xv.x * w[k4 * 4 + 0] + xv.y * w[k4 * 4 + 1]
             + xv.z * w[k4 * 4 + 2] + xv.w * w[k4 * 4 + 3];
      }
      xcol[n] = acc;
    }
  }

  // ---- layer1 logits: al[n,h] = x[n,:] . u1[h,:]  (56 lanes) ----
  if (tid < 56) {
    const int n = tid >> 2, h = (tid >> 1) & 1, sd = tid & 1;
    const float* uu = u + (sd ? U_UD1 : U_US1) + h * IN_F;
    float s = 0.f;
#pragma unroll
    for (int k = 0; k < IN_F; ++k) s += xs[n * XS_S + k] * uu[k];
    (sd ? ald : als)[n * 2 + h] = s;
  }
  __syncthreads();

  // ---- layer1 softmax (28 lanes: (j,h)) ----
  if (tid < NODES * 2) {
    const int h = tid & 1;
    const float ad = ald[tid];
    float a[NODES]; float m = -1e30f;
#pragma unroll
    for (int i = 0; i < NODES; ++i) {
      float v = als[i * 2 + h] + ad;
      v = v > 0.f ? v : SLOPE * v;
      a[i] = v; m = fmaxf(m, v);
    }
    float den = 0.f;
#pragma unroll
    for (int i = 0; i < NODES; ++i) { a[i] = __expf(a[i] - m); den += a[i]; }
    const float r = 1.f / den;
#pragma unroll
    for (int i = 0; i < NODES; ++i) watt[i * 28 + tid] = a[i] * r;
  }
  __syncthreads();

  // ---- layer1 aggregate: wave wid does nodes [7*wid, 7*wid+7) ----
  {
    const int h = lane >> 5, f5 = lane & 31;
    const float bb = b1[f5];
#pragma unroll
    for (int tt = 0; tt < NODES / 2; ++tt) {
      const int n = wid * (NODES / 2) + tt;
      float o = 0.f;
#pragma unroll
      for (int i = 0; i < NODES; ++i)
        o += watt[i * 28 + n * 2 + h] * xcol[i];
      const float oo = __shfl_xor(o, 32);
      if (h == 0) {
        const float v = 0.5f * (o + oo) + bb;
        h1s[n * H1_S + f5] = v > 0.f ? v : expm1f(v);
      }
    }
  }
  __syncthreads();

  // ---- layer2 GEMM: col = tid (128 cols, one per thread) ----
  float x2c[NODES];
  {
    float w2[HID1];
#pragma unroll
    for (int k = 0; k < HID1; ++k) w2[k] = W2[k * 128 + tid];
#pragma unroll
    for (int n = 0; n < NODES; ++n) {
      float acc = 0.f;
#pragma unroll
      for (int k4 = 0; k4 < HID1 / 4; ++k4) {
        const float4 hv = *(const float4*)&h1s[n * H1_S + k4 * 4];
        acc += hv.x * w2[k4 * 4 + 0] + hv.y * w2[k4 * 4 + 1]
             + hv.z * w2[k4 * 4 + 2] + hv.w * w2[k4 * 4 + 3];
      }
      x2c[n] = acc;
    }
  }

  // ---- layer2 logits: al[n,h] = h1[n,:] . u2[h,:]  (56 lanes) ----
  if (tid < 56) {
    const int n = tid >> 2, h = (tid >> 1) & 1, sd = tid & 1;
    const float* uu = u + (sd ? U_UD2 : U_US2) + h * HID1;
    float s = 0.f;
#pragma unroll
    for (int k = 0; k < HID1; ++k) s += h1s[n * H1_S + k] * uu[k];
    (sd ? ald : als)[n * 2 + h] = s;
  }
  __syncthreads();

  // ---- layer2 softmax ----
  if (tid < NODES * 2) {
    const int h = tid & 1;
    const float ad = ald[tid];
    float a[NODES]; float m = -1e30f;
#pragma unroll
    for (int i = 0; i < NODES; ++i) {
      float v = als[i * 2 + h] + ad;
      v = v > 0.f ? v : SLOPE * v;
      a[i] = v; m = fmaxf(m, v);
    }
    float den = 0.f;
#pragma unroll
    for (int i = 0; i < NODES; ++i) { a[i] = __expf(a[i] - m); den += a[i]; }
    const float r = 1.f / den;
#pragma unroll
    for (int i = 0; i < NODES; ++i) watt[i * 28 + tid] = a[i] * r;
  }
  __syncthreads();

  // ---- layer2 aggregate: head = wid; cross-wave combine via LDS ----
  {
    float agg[NODES];
#pragma unroll
    for (int n = 0; n < NODES; ++n) {
      float o = 0.f;
#pragma unroll
      for (int i = 0; i < NODES; ++i)
        o += watt[i * 28 + n * 2 + wid] * x2c[i];
      agg[n] = o;
    }
    if (wid == 1) {
#pragma unroll
      for (int n = 0; n < NODES; ++n) h2s[n * H2_S + lane] = agg[n];
    }
    __syncthreads();
    if (wid == 0) {
      const float bb = b2[lane];
#pragma unroll
      for (int n = 0; n < NODES; ++n)
        h2s[n * H2_S + lane] = 0.5f * (agg[n] + h2s[n * H2_S + lane]) + bb;
    }
  }
  __syncthreads();

  // ---- per-node MLP layer 1 (112 lanes) ----
  if (tid < NODES * 8) {
    const int k = tid >> 3, e = tid & 7;
    float acc = bf1[k * 8 + e];
#pragma unroll 8
    for (int f = 0; f < HID2; ++f)
      acc += h2s[k * H2_S + f] * Wf1[(k * HID2 + f) * 8 + e];
    hhs[tid] = fmaxf(acc, 0.f);
  }
  __syncthreads();

  // ---- per-node MLP layer 2 (336 outputs) ----
  for (int idx = tid; idx < NODES * OUT_F; idx += 128) {
    const int k = idx / OUT_F, o = idx - k * OUT_F;
    float acc = bf2[k * OUT_F + o];
#pragma unroll
    for (int e = 0; e < 8; ++e)
      acc += hhs[k * 8 + e] * Wf2[(k * 8 + e) * OUT_F + o];
    out[(size_t)k * ngraphs * OUT_F + (size_t)g * OUT_F + o] =
        1.f / (1.f + __expf(-acc));
  }
}

extern "C" void kernel_launch(void* const* d_in, const int* in_sizes, int n_in,
                              void* d_out, int out_size, void* d_ws, size_t ws_size,
                              hipStream_t stream) {
  const float* x      = (const float*)d_in[0];
  const float* y      = (const float*)d_in[1];
  // d_in[2] = edge_index, d_in[3] = batch : structure fixed, unused
  const float* W1     = (const float*)d_in[4];
  const float* a_src1 = (const float*)d_in[5];
  const float* a_dst1 = (const float*)d_in[6];
  const float* b1     = (const float*)d_in[7];
  const float* W2     = (const float*)d_in[8];
  const float* a_src2 = (const float*)d_in[9];
  const float* a_dst2 = (const float*)d_in[10];
  const float* b2     = (const float*)d_in[11];
  const float* Wf1    = (const float*)d_in[12];
  const float* bf1    = (const float*)d_in[13];
  const float* Wf2    = (const float*)d_in[14];
  const float* bf2    = (const float*)d_in[15];
  float* out = (float*)d_out;
  float* u   = (float*)d_ws;

  const int nnodes  = in_sizes[0] / IN_F;
  const int ngraphs = nnodes / NODES;

  hipLaunchKernelGGL(compute_uvecs, dim3(1), dim3(256), 0, stream,
                     W1, a_src1, a_dst1, W2, a_src2, a_dst2, u);
  hipLaunchKernelGGL(gnn_fused, dim3(ngraphs), dim3(128), 0, stream,
                     x, y, W1, b1, W2, b2, Wf1, bf1, Wf2, bf2, u, out, ngraphs);
}

// Round 6
// 58.758 us; speedup vs baseline: 5.6395x; 5.4600x over previous
//
#include <hip/hip_runtime.h>

#define NODES 14
#define IN_F 24
#define HID1 32
#define HID2 64
#define OUT_F 24
#define SLOPE 0.2f

#define XS_S 28   // xs stride   (float4-aligned)
#define H1_S 36   // h1s stride  (float4-aligned)
#define H2_S 68   // h2s stride

// u-vector layout in d_ws: us1[48] ud1[48] us2[64] ud2[64]  (224 floats)
#define U_US1 0
#define U_UD1 48
#define U_US2 96
#define U_UD2 160
#define U_TOT 224

// ---- kernel 1: precompute u = W @ a  (graph-invariant, once) ----
__global__ __launch_bounds__(256) void compute_uvecs(
    const float* __restrict__ W1, const float* __restrict__ a_src1,
    const float* __restrict__ a_dst1,
    const float* __restrict__ W2, const float* __restrict__ a_src2,
    const float* __restrict__ a_dst2, float* __restrict__ u)
{
  const int tid = threadIdx.x;
  if (tid < 96) {
    const int sd = (tid >= 48), r = tid - sd * 48;
    const int h = (r >= IN_F), k = r - h * IN_F;
    const float* av = sd ? a_dst1 : a_src1;
    float s = 0.f;
#pragma unroll
    for (int f = 0; f < HID1; ++f)
      s += W1[k * 64 + h * HID1 + f] * av[h * HID1 + f];
    u[(sd ? U_UD1 : U_US1) + h * IN_F + k] = s;
  } else if (tid < 224) {
    const int j = tid - 96;
    const int sd = (j >= 64), r = j - sd * 64;
    const int h = (r >= HID1), k = r - h * HID1;
    const float* av = sd ? a_dst2 : a_src2;
    float s = 0.f;
#pragma unroll
    for (int f = 0; f < HID2; ++f)
      s += W2[k * 128 + h * HID2 + f] * av[h * HID2 + f];
    u[(sd ? U_UD2 : U_US2) + h * HID1 + k] = s;
  }
}

// ---- kernel 2: fused GNN+MLP, one graph per 128-thread block ----
// NOTE: no min-waves arg — R4/R5 showed forcing it (4 -> VGPR cap 64)
// causes ~1 GB of scratch spill traffic. Unconstrained, this structure
// fits in <100 VGPRs (R2 measured 52 for the 64-thread variant).
__global__ __launch_bounds__(128) void gnn_fused(
    const float* __restrict__ x, const float* __restrict__ y,
    const float* __restrict__ W1, const float* __restrict__ b1,
    const float* __restrict__ W2, const float* __restrict__ b2,
    const float* __restrict__ Wf1, const float* __restrict__ bf1,
    const float* __restrict__ Wf2, const float* __restrict__ bf2,
    const float* __restrict__ uvec,
    float* __restrict__ out, int ngraphs)
{
  const int g = blockIdx.x;
  const int tid = threadIdx.x;
  const int lane = tid & 63;
  const int wid = tid >> 6;

  __shared__ float u[U_TOT];                         // 224
  __shared__ __align__(16) float xs[NODES * XS_S];   // 392
  __shared__ __align__(16) float h1s[NODES * H1_S];  // 504
  __shared__ float h2s[NODES * H2_S];                // 952
  __shared__ float watt[NODES * 28];                 // 392 [i][j][h]
  __shared__ float als[28], ald[28];
  __shared__ float hhs[112];

  // ---- stage u + x; y-copy (independent, hides store latency) ----
  if (tid < (NODES * OUT_F) / 4) {
    const float4* y4 = (const float4*)(y + (size_t)g * (NODES * OUT_F));
    float4* o4 = (float4*)(out + (size_t)NODES * ngraphs * OUT_F
                               + (size_t)g * (NODES * OUT_F));
    o4[tid] = y4[tid];
  }
  for (int i = tid; i < U_TOT; i += 128) u[i] = uvec[i];
  if (tid < (NODES * IN_F) / 4) {
    const float4 v = *(const float4*)(x + (size_t)g * (NODES * IN_F) + tid * 4);
    const int n = (tid * 4) / IN_F, k = (tid * 4) - n * IN_F;
    *(float4*)&xs[n * XS_S + k] = v;
  }
  __syncthreads();

  // ---- layer1 GEMM: col = lane (both waves duplicate; keeps xcol local) ----
  float xcol[NODES];
  {
    float w[IN_F];
#pragma unroll
    for (int k = 0; k < IN_F; ++k) w[k] = W1[k * 64 + lane];
#pragma unroll
    for (int n = 0; n < NODES; ++n) {
      float acc = 0.f;
#pragma unroll
      for (int k4 = 0; k4 < IN_F / 4; ++k4) {
        const float4 xv = *(const float4*)&xs[n * XS_S + k4 * 4];
        acc += xv.x * w[k4 * 4 + 0] + xv.y * w[k4 * 4 + 1]
             + xv.z * w[k4 * 4 + 2] + xv.w * w[k4 * 4 + 3];
      }
      xcol[n] = acc;
    }
  }

  // ---- layer1 logits: al[n,h] = x[n,:] . u1[h,:]  (56 lanes) ----
  if (tid < 56) {
    const int n = tid >> 2, h = (tid >> 1) & 1, sd = tid & 1;
    const float* uu = u + (sd ? U_UD1 : U_US1) + h * IN_F;
    float s = 0.f;
#pragma unroll
    for (int k = 0; k < IN_F; ++k) s += xs[n * XS_S + k] * uu[k];
    (sd ? ald : als)[n * 2 + h] = s;
  }
  __syncthreads();

  // ---- layer1 softmax (28 lanes: (j,h)) ----
  if (tid < NODES * 2) {
    const int h = tid & 1;
    const float ad = ald[tid];
    float a[NODES]; float m = -1e30f;
#pragma unroll
    for (int i = 0; i < NODES; ++i) {
      float v = als[i * 2 + h] + ad;
      v = v > 0.f ? v : SLOPE * v;
      a[i] = v; m = fmaxf(m, v);
    }
    float den = 0.f;
#pragma unroll
    for (int i = 0; i < NODES; ++i) { a[i] = __expf(a[i] - m); den += a[i]; }
    const float r = 1.f / den;
#pragma unroll
    for (int i = 0; i < NODES; ++i) watt[i * 28 + tid] = a[i] * r;
  }
  __syncthreads();

  // ---- layer1 aggregate: wave wid does nodes [7*wid, 7*wid+7) ----
  {
    const int h = lane >> 5, f5 = lane & 31;
    const float bb = b1[f5];
#pragma unroll
    for (int tt = 0; tt < NODES / 2; ++tt) {
      const int n = wid * (NODES / 2) + tt;
      float o = 0.f;
#pragma unroll
      for (int i = 0; i < NODES; ++i)
        o += watt[i * 28 + n * 2 + h] * xcol[i];
      const float oo = __shfl_xor(o, 32);
      if (h == 0) {
        const float v = 0.5f * (o + oo) + bb;
        h1s[n * H1_S + f5] = v > 0.f ? v : expm1f(v);
      }
    }
  }
  __syncthreads();

  // ---- layer2 GEMM: col = tid (128 cols, one per thread) ----
  float x2c[NODES];
  {
    float w2[HID1];
#pragma unroll
    for (int k = 0; k < HID1; ++k) w2[k] = W2[k * 128 + tid];
#pragma unroll
    for (int n = 0; n < NODES; ++n) {
      float acc = 0.f;
#pragma unroll
      for (int k4 = 0; k4 < HID1 / 4; ++k4) {
        const float4 hv = *(const float4*)&h1s[n * H1_S + k4 * 4];
        acc += hv.x * w2[k4 * 4 + 0] + hv.y * w2[k4 * 4 + 1]
             + hv.z * w2[k4 * 4 + 2] + hv.w * w2[k4 * 4 + 3];
      }
      x2c[n] = acc;
    }
  }

  // ---- layer2 logits: al[n,h] = h1[n,:] . u2[h,:]  (56 lanes) ----
  if (tid < 56) {
    const int n = tid >> 2, h = (tid >> 1) & 1, sd = tid & 1;
    const float* uu = u + (sd ? U_UD2 : U_US2) + h * HID1;
    float s = 0.f;
#pragma unroll
    for (int k = 0; k < HID1; ++k) s += h1s[n * H1_S + k] * uu[k];
    (sd ? ald : als)[n * 2 + h] = s;
  }
  __syncthreads();

  // ---- layer2 softmax ----
  if (tid < NODES * 2) {
    const int h = tid & 1;
    const float ad = ald[tid];
    float a[NODES]; float m = -1e30f;
#pragma unroll
    for (int i = 0; i < NODES; ++i) {
      float v = als[i * 2 + h] + ad;
      v = v > 0.f ? v : SLOPE * v;
      a[i] = v; m = fmaxf(m, v);
    }
    float den = 0.f;
#pragma unroll
    for (int i = 0; i < NODES; ++i) { a[i] = __expf(a[i] - m); den += a[i]; }
    const float r = 1.f / den;
#pragma unroll
    for (int i = 0; i < NODES; ++i) watt[i * 28 + tid] = a[i] * r;
  }
  __syncthreads();

  // ---- layer2 aggregate: head = wid; cross-wave combine via LDS ----
  {
    float agg[NODES];
#pragma unroll
    for (int n = 0; n < NODES; ++n) {
      float o = 0.f;
#pragma unroll
      for (int i = 0; i < NODES; ++i)
        o += watt[i * 28 + n * 2 + wid] * x2c[i];
      agg[n] = o;
    }
    if (wid == 1) {
#pragma unroll
      for (int n = 0; n < NODES; ++n) h2s[n * H2_S + lane] = agg[n];
    }
    __syncthreads();
    if (wid == 0) {
      const float bb = b2[lane];
#pragma unroll
      for (int n = 0; n < NODES; ++n)
        h2s[n * H2_S + lane] = 0.5f * (agg[n] + h2s[n * H2_S + lane]) + bb;
    }
  }
  __syncthreads();

  // ---- per-node MLP layer 1 (112 lanes) ----
  if (tid < NODES * 8) {
    const int k = tid >> 3, e = tid & 7;
    float acc = bf1[k * 8 + e];
#pragma unroll 8
    for (int f = 0; f < HID2; ++f)
      acc += h2s[k * H2_S + f] * Wf1[(k * HID2 + f) * 8 + e];
    hhs[tid] = fmaxf(acc, 0.f);
  }
  __syncthreads();

  // ---- per-node MLP layer 2 (336 outputs) ----
  for (int idx = tid; idx < NODES * OUT_F; idx += 128) {
    const int k = idx / OUT_F, o = idx - k * OUT_F;
    float acc = bf2[k * OUT_F + o];
#pragma unroll
    for (int e = 0; e < 8; ++e)
      acc += hhs[k * 8 + e] * Wf2[(k * 8 + e) * OUT_F + o];
    out[(size_t)k * ngraphs * OUT_F + (size_t)g * OUT_F + o] =
        1.f / (1.f + __expf(-acc));
  }
}

extern "C" void kernel_launch(void* const* d_in, const int* in_sizes, int n_in,
                              void* d_out, int out_size, void* d_ws, size_t ws_size,
                              hipStream_t stream) {
  const float* x      = (const float*)d_in[0];
  const float* y      = (const float*)d_in[1];
  // d_in[2] = edge_index, d_in[3] = batch : structure fixed, unused
  const float* W1     = (const float*)d_in[4];
  const float* a_src1 = (const float*)d_in[5];
  const float* a_dst1 = (const float*)d_in[6];
  const float* b1     = (const float*)d_in[7];
  const float* W2     = (const float*)d_in[8];
  const float* a_src2 = (const float*)d_in[9];
  const float* a_dst2 = (const float*)d_in[10];
  const float* b2     = (const float*)d_in[11];
  const float* Wf1    = (const float*)d_in[12];
  const float* bf1    = (const float*)d_in[13];
  const float* Wf2    = (const float*)d_in[14];
  const float* bf2    = (const float*)d_in[15];
  float* out = (float*)d_out;
  float* u   = (float*)d_ws;

  const int nnodes  = in_sizes[0] / IN_F;
  const int ngraphs = nnodes / NODES;

  hipLaunchKernelGGL(compute_uvecs, dim3(1), dim3(256), 0, stream,
                     W1, a_src1, a_dst1, W2, a_src2, a_dst2, u);
  hipLaunchKernelGGL(gnn_fused, dim3(ngraphs), dim3(128), 0, stream,
                     x, y, W1, b1, W2, b2, Wf1, bf1, Wf2, bf2, u, out, ngraphs);
}

// Round 7
// 31.537 us; speedup vs baseline: 10.5071x; 1.8631x over previous
//
#include <hip/hip_runtime.h>

#define NODES 14
#define IN_F 24
#define HID1 32
#define HID2 64
#define OUT_F 24
#define SLOPE 0.2f

#define XS_S 28   // xs stride   (float4-aligned)
#define H1_S 36   // h1s stride  (float4-aligned)
#define H2_S 68   // h2s stride

// u-vector layout in d_ws: us1[48] ud1[48] us2[64] ud2[64]  (224 floats)
#define U_US1 0
#define U_UD1 48
#define U_US2 96
#define U_UD2 160
#define U_TOT 224

#define PHASE_FENCE() __builtin_amdgcn_sched_barrier(0)

// ---- kernel 1: precompute u = W @ a  (graph-invariant, once) ----
__global__ __launch_bounds__(256) void compute_uvecs(
    const float* __restrict__ W1, const float* __restrict__ a_src1,
    const float* __restrict__ a_dst1,
    const float* __restrict__ W2, const float* __restrict__ a_src2,
    const float* __restrict__ a_dst2, float* __restrict__ u)
{
  const int tid = threadIdx.x;
  if (tid < 96) {
    const int sd = (tid >= 48), r = tid - sd * 48;
    const int h = (r >= IN_F), k = r - h * IN_F;
    const float* av = sd ? a_dst1 : a_src1;
    float s = 0.f;
#pragma unroll
    for (int f = 0; f < HID1; ++f)
      s += W1[k * 64 + h * HID1 + f] * av[h * HID1 + f];
    u[(sd ? U_UD1 : U_US1) + h * IN_F + k] = s;
  } else if (tid < 224) {
    const int j = tid - 96;
    const int sd = (j >= 64), r = j - sd * 64;
    const int h = (r >= HID1), k = r - h * HID1;
    const float* av = sd ? a_dst2 : a_src2;
    float s = 0.f;
#pragma unroll
    for (int f = 0; f < HID2; ++f)
      s += W2[k * 128 + h * HID2 + f] * av[h * HID2 + f];
    u[(sd ? U_UD2 : U_US2) + h * HID1 + k] = s;
  }
}

// ---- kernel 2: fused GNN+MLP, one graph per 128-thread block ----
// No launch_bounds min-arg (R4/R5: forcing it causes ~1 GB spill traffic).
// sched_barrier(0) at phase boundaries stops the scheduler from hoisting
// weight loads across phases (R6: unconstrained hoisting -> VGPR 256,
// occupancy 10%). Peak liveness should now be the layer2-GEMM phase (~70).
__global__ __launch_bounds__(128) void gnn_fused(
    const float* __restrict__ x, const float* __restrict__ y,
    const float* __restrict__ W1, const float* __restrict__ b1,
    const float* __restrict__ W2, const float* __restrict__ b2,
    const float* __restrict__ Wf1, const float* __restrict__ bf1,
    const float* __restrict__ Wf2, const float* __restrict__ bf2,
    const float* __restrict__ uvec,
    float* __restrict__ out, int ngraphs)
{
  const int g = blockIdx.x;
  const int tid = threadIdx.x;
  const int lane = tid & 63;
  const int wid = tid >> 6;

  __shared__ float u[U_TOT];                         // 224
  __shared__ __align__(16) float xs[NODES * XS_S];   // 392
  __shared__ __align__(16) float h1s[NODES * H1_S];  // 504
  __shared__ float h2s[NODES * H2_S];                // 952
  __shared__ float watt[NODES * 28];                 // 392 [i][j][h]
  __shared__ float als[28], ald[28];
  __shared__ float hhs[112];

  // ---- stage u + x; y-copy (independent, hides store latency) ----
  if (tid < (NODES * OUT_F) / 4) {
    const float4* y4 = (const float4*)(y + (size_t)g * (NODES * OUT_F));
    float4* o4 = (float4*)(out + (size_t)NODES * ngraphs * OUT_F
                               + (size_t)g * (NODES * OUT_F));
    o4[tid] = y4[tid];
  }
  for (int i = tid; i < U_TOT; i += 128) u[i] = uvec[i];
  if (tid < (NODES * IN_F) / 4) {
    const float4 v = *(const float4*)(x + (size_t)g * (NODES * IN_F) + tid * 4);
    const int n = (tid * 4) / IN_F, k = (tid * 4) - n * IN_F;
    *(float4*)&xs[n * XS_S + k] = v;
  }
  __syncthreads();
  PHASE_FENCE();

  // ---- layer1 GEMM: col = lane (both waves duplicate; keeps xcol local) ----
  float xcol[NODES];
  {
    float w[IN_F];
#pragma unroll
    for (int k = 0; k < IN_F; ++k) w[k] = W1[k * 64 + lane];
#pragma unroll 2
    for (int n = 0; n < NODES; ++n) {
      float acc = 0.f;
#pragma unroll
      for (int k4 = 0; k4 < IN_F / 4; ++k4) {
        const float4 xv = *(const float4*)&xs[n * XS_S + k4 * 4];
        acc += xv.x * w[k4 * 4 + 0] + xv.y * w[k4 * 4 + 1]
             + xv.z * w[k4 * 4 + 2] + xv.w * w[k4 * 4 + 3];
      }
      xcol[n] = acc;
    }
  }
  PHASE_FENCE();

  // ---- layer1 logits: al[n,h] = x[n,:] . u1[h,:]  (56 lanes) ----
  if (tid < 56) {
    const int n = tid >> 2, h = (tid >> 1) & 1, sd = tid & 1;
    const float* uu = u + (sd ? U_UD1 : U_US1) + h * IN_F;
    float s = 0.f;
#pragma unroll
    for (int k = 0; k < IN_F; ++k) s += xs[n * XS_S + k] * uu[k];
    (sd ? ald : als)[n * 2 + h] = s;
  }
  __syncthreads();
  PHASE_FENCE();

  // ---- layer1 softmax (28 lanes: (j,h)) ----
  if (tid < NODES * 2) {
    const int h = tid & 1;
    const float ad = ald[tid];
    float a[NODES]; float m = -1e30f;
#pragma unroll
    for (int i = 0; i < NODES; ++i) {
      float v = als[i * 2 + h] + ad;
      v = v > 0.f ? v : SLOPE * v;
      a[i] = v; m = fmaxf(m, v);
    }
    float den = 0.f;
#pragma unroll
    for (int i = 0; i < NODES; ++i) { a[i] = __expf(a[i] - m); den += a[i]; }
    const float r = 1.f / den;
#pragma unroll
    for (int i = 0; i < NODES; ++i) watt[i * 28 + tid] = a[i] * r;
  }
  __syncthreads();
  PHASE_FENCE();

  // ---- layer1 aggregate: wave wid does nodes [7*wid, 7*wid+7) ----
  {
    const int h = lane >> 5, f5 = lane & 31;
    const float bb = b1[f5];
#pragma unroll 2
    for (int tt = 0; tt < NODES / 2; ++tt) {
      const int n = wid * (NODES / 2) + tt;
      float o = 0.f;
#pragma unroll
      for (int i = 0; i < NODES; ++i)
        o += watt[i * 28 + n * 2 + h] * xcol[i];
      const float oo = __shfl_xor(o, 32);
      if (h == 0) {
        const float v = 0.5f * (o + oo) + bb;
        h1s[n * H1_S + f5] = v > 0.f ? v : expm1f(v);
      }
    }
  }
  __syncthreads();
  PHASE_FENCE();

  // ---- layer2 GEMM: col = tid (128 cols, one per thread) ----
  float x2c[NODES];
  {
    float w2[HID1];
#pragma unroll
    for (int k = 0; k < HID1; ++k) w2[k] = W2[k * 128 + tid];
#pragma unroll 2
    for (int n = 0; n < NODES; ++n) {
      float acc = 0.f;
#pragma unroll
      for (int k4 = 0; k4 < HID1 / 4; ++k4) {
        const float4 hv = *(const float4*)&h1s[n * H1_S + k4 * 4];
        acc += hv.x * w2[k4 * 4 + 0] + hv.y * w2[k4 * 4 + 1]
             + hv.z * w2[k4 * 4 + 2] + hv.w * w2[k4 * 4 + 3];
      }
      x2c[n] = acc;
    }
  }
  PHASE_FENCE();

  // ---- layer2 logits: al[n,h] = h1[n,:] . u2[h,:]  (56 lanes) ----
  if (tid < 56) {
    const int n = tid >> 2, h = (tid >> 1) & 1, sd = tid & 1;
    const float* uu = u + (sd ? U_UD2 : U_US2) + h * HID1;
    float s = 0.f;
#pragma unroll
    for (int k = 0; k < HID1; ++k) s += h1s[n * H1_S + k] * uu[k];
    (sd ? ald : als)[n * 2 + h] = s;
  }
  __syncthreads();
  PHASE_FENCE();

  // ---- layer2 softmax ----
  if (tid < NODES * 2) {
    const int h = tid & 1;
    const float ad = ald[tid];
    float a[NODES]; float m = -1e30f;
#pragma unroll
    for (int i = 0; i < NODES; ++i) {
      float v = als[i * 2 + h] + ad;
      v = v > 0.f ? v : SLOPE * v;
      a[i] = v; m = fmaxf(m, v);
    }
    float den = 0.f;
#pragma unroll
    for (int i = 0; i < NODES; ++i) { a[i] = __expf(a[i] - m); den += a[i]; }
    const float r = 1.f / den;
#pragma unroll
    for (int i = 0; i < NODES; ++i) watt[i * 28 + tid] = a[i] * r;
  }
  __syncthreads();
  PHASE_FENCE();

  // ---- layer2 aggregate: head = wid; cross-wave combine via LDS ----
  {
    float agg[NODES];
#pragma unroll
    for (int n = 0; n < NODES; ++n) {
      float o = 0.f;
#pragma unroll
      for (int i = 0; i < NODES; ++i)
        o += watt[i * 28 + n * 2 + wid] * x2c[i];
      agg[n] = o;
    }
    if (wid == 1) {
#pragma unroll
      for (int n = 0; n < NODES; ++n) h2s[n * H2_S + lane] = agg[n];
    }
    __syncthreads();
    if (wid == 0) {
      const float bb = b2[lane];
#pragma unroll
      for (int n = 0; n < NODES; ++n)
        h2s[n * H2_S + lane] = 0.5f * (agg[n] + h2s[n * H2_S + lane]) + bb;
    }
  }
  __syncthreads();
  PHASE_FENCE();

  // ---- per-node MLP layer 1 (112 lanes) ----
  if (tid < NODES * 8) {
    const int k = tid >> 3, e = tid & 7;
    float acc = bf1[k * 8 + e];
#pragma unroll 8
    for (int f = 0; f < HID2; ++f)
      acc += h2s[k * H2_S + f] * Wf1[(k * HID2 + f) * 8 + e];
    hhs[tid] = fmaxf(acc, 0.f);
  }
  __syncthreads();
  PHASE_FENCE();

  // ---- per-node MLP layer 2 (336 outputs) ----
  for (int idx = tid; idx < NODES * OUT_F; idx += 128) {
    const int k = idx / OUT_F, o = idx - k * OUT_F;
    float acc = bf2[k * OUT_F + o];
#pragma unroll
    for (int e = 0; e < 8; ++e)
      acc += hhs[k * 8 + e] * Wf2[(k * 8 + e) * OUT_F + o];
    out[(size_t)k * ngraphs * OUT_F + (size_t)g * OUT_F + o] =
        1.f / (1.f + __expf(-acc));
  }
}

extern "C" void kernel_launch(void* const* d_in, const int* in_sizes, int n_in,
                              void* d_out, int out_size, void* d_ws, size_t ws_size,
                              hipStream_t stream) {
  const float* x      = (const float*)d_in[0];
  const float* y      = (const float*)d_in[1];
  // d_in[2] = edge_index, d_in[3] = batch : structure fixed, unused
  const float* W1     = (const float*)d_in[4];
  const float* a_src1 = (const float*)d_in[5];
  const float* a_dst1 = (const float*)d_in[6];
  const float* b1     = (const float*)d_in[7];
  const float* W2     = (const float*)d_in[8];
  const float* a_src2 = (const float*)d_in[9];
  const float* a_dst2 = (const float*)d_in[10];
  const float* b2     = (const float*)d_in[11];
  const float* Wf1    = (const float*)d_in[12];
  const float* bf1    = (const float*)d_in[13];
  const float* Wf2    = (const float*)d_in[14];
  const float* bf2    = (const float*)d_in[15];
  float* out = (float*)d_out;
  float* u   = (float*)d_ws;

  const int nnodes  = in_sizes[0] / IN_F;
  const int ngraphs = nnodes / NODES;

  hipLaunchKernelGGL(compute_uvecs, dim3(1), dim3(256), 0, stream,
                     W1, a_src1, a_dst1, W2, a_src2, a_dst2, u);
  hipLaunchKernelGGL(gnn_fused, dim3(ngraphs), dim3(128), 0, stream,
                     x, y, W1, b1, W2, b2, Wf1, bf1, Wf2, bf2, u, out, ngraphs);
}